// Round 3
// baseline (358.272 us; speedup 1.0000x reference)
//
#include <hip/hip_runtime.h>
#include <stdint.h>

// GPT causal self-attention block. B=8, T=1024, C=768, H=8, D=96.
// Inputs/outputs are FLOAT32 (per reference setup_inputs). We convert x and
// the two weight matrices to bf16 in workspace, run MFMA bf16 GEMMs + fused
// flash attention with fp32 accumulation, and write the final output as f32.
// Causal mask input (int32) ignored (causality computed arithmetically).

typedef unsigned short ushort_t;
typedef __attribute__((ext_vector_type(8))) short short8;     // 8 bf16 = 4 VGPRs
typedef __attribute__((ext_vector_type(4))) float floatx4;    // MFMA C/D frag
typedef __attribute__((ext_vector_type(4))) unsigned short ushort4v;

#define MFMA16(a, b, c) __builtin_amdgcn_mfma_f32_16x16x32_bf16(a, b, c, 0, 0, 0)
#define NEG_BIG (-1e30f)

__device__ __forceinline__ unsigned short f2bf(float f) {
  union { float f; unsigned int u; } v; v.f = f;
  unsigned int r = (v.u + 0x7FFFu + ((v.u >> 16) & 1u)) >> 16;  // RNE
  return (unsigned short)r;
}

// ---------------------------------------------------------------------------
// f32 -> bf16 convert (vectorized, grid-stride-free; n divisible by 4 here)
// ---------------------------------------------------------------------------
__global__ __launch_bounds__(256) void cvt_f32_bf16(
    const float* __restrict__ in, ushort_t* __restrict__ out, int n)
{
  int i = (blockIdx.x * 256 + threadIdx.x) * 4;
  if (i + 3 < n) {
    float4 v = *(const float4*)(in + i);
    ushort4v o;
    o.x = f2bf(v.x); o.y = f2bf(v.y); o.z = f2bf(v.z); o.w = f2bf(v.w);
    *(ushort4v*)(out + i) = o;
  } else {
    for (; i < n; ++i) out[i] = f2bf(in[i]);
  }
}

// ---------------------------------------------------------------------------
// GEMM: C[m][n] = sum_k A[m][k] * W[n][k] + bias[n]   (both K-contiguous)
// m97 structure: 128x128 tile, BK=32, global_load_lds width=16, 4 waves 2x2.
// OutT = ushort_t (bf16) or float.
// ---------------------------------------------------------------------------
template <typename OutT>
__global__ __launch_bounds__(256) void gemm_bt_bias(
    const ushort_t* __restrict__ A,   // M x K bf16
    const ushort_t* __restrict__ W,   // N x K bf16
    const float* __restrict__ bias,   // N f32
    OutT* __restrict__ C,             // M x N
    int M, int N, int K)
{
  __shared__ ushort_t As[128 * 32];
  __shared__ ushort_t Bs[128 * 32];

  const int tid  = threadIdx.x;
  const int lane = tid & 63;
  const int l15  = lane & 15;
  const int quad = lane >> 4;
  const int wid  = tid >> 6;
  const int m0 = blockIdx.x * 128;
  const int n0 = blockIdx.y * 128;
  const int wm = (wid >> 1) * 64;
  const int wn = (wid & 1) * 64;
  const int srow = tid >> 2;        // 0..63
  const int scol = (tid & 3) * 8;   // 0,8,16,24

  floatx4 acc[4][4] = {};

  const ushort_t* gA = A + (size_t)(m0 + srow) * K + scol;
  const ushort_t* gB = W + (size_t)(n0 + srow) * K + scol;
  ushort_t* lA = &As[wid * 512];    // wave-uniform LDS base
  ushort_t* lB = &Bs[wid * 512];

  for (int k0 = 0; k0 < K; k0 += 32) {
    __builtin_amdgcn_global_load_lds(
        (const __attribute__((address_space(1))) void*)gA,
        (__attribute__((address_space(3))) void*)lA, 16, 0, 0);
    __builtin_amdgcn_global_load_lds(
        (const __attribute__((address_space(1))) void*)(gA + (size_t)64 * K),
        (__attribute__((address_space(3))) void*)(lA + 64 * 32), 16, 0, 0);
    __builtin_amdgcn_global_load_lds(
        (const __attribute__((address_space(1))) void*)gB,
        (__attribute__((address_space(3))) void*)lB, 16, 0, 0);
    __builtin_amdgcn_global_load_lds(
        (const __attribute__((address_space(1))) void*)(gB + (size_t)64 * K),
        (__attribute__((address_space(3))) void*)(lB + 64 * 32), 16, 0, 0);
    gA += 32; gB += 32;
    __syncthreads();

    short8 af[4], bf[4];
#pragma unroll
    for (int t = 0; t < 4; ++t)
      af[t] = *(const short8*)&As[(wm + t * 16 + l15) * 32 + quad * 8];
#pragma unroll
    for (int t = 0; t < 4; ++t)
      bf[t] = *(const short8*)&Bs[(wn + t * 16 + l15) * 32 + quad * 8];
#pragma unroll
    for (int tm = 0; tm < 4; ++tm)
#pragma unroll
      for (int tn = 0; tn < 4; ++tn)
        acc[tm][tn] = MFMA16(af[tm], bf[tn], acc[tm][tn]);
    __syncthreads();
  }

  // epilogue: C/D layout col=lane&15, row=quad*4+reg
#pragma unroll
  for (int tn = 0; tn < 4; ++tn) {
    const int gc = n0 + wn + tn * 16 + l15;
    const float bv = bias[gc];
#pragma unroll
    for (int tm = 0; tm < 4; ++tm) {
      const int gr = m0 + wm + tm * 16 + quad * 4;
#pragma unroll
      for (int r = 0; r < 4; ++r) {
        const float val = acc[tm][tn][r] + bv;
        if constexpr (sizeof(OutT) == 2)
          C[(size_t)(gr + r) * N + gc] = (OutT)f2bf(val);
        else
          C[(size_t)(gr + r) * N + gc] = (OutT)val;
      }
    }
  }
}

// ---------------------------------------------------------------------------
// Fused causal flash attention. qkv: (B*T, 2304) bf16 rows = [q|k|v], head h
// at col h*96. One block = one (b,h) and 64 q rows; wave w owns 16 q rows.
// ---------------------------------------------------------------------------
__global__ __launch_bounds__(256) void attn_fused(
    const ushort_t* __restrict__ qkv,  // (B*T) x 2304 bf16
    ushort_t* __restrict__ y)          // (B*T) x 768 bf16
{
  __shared__ ushort_t Ks[32 * 96];     // K tile, row-major [key][d]
  __shared__ ushort_t Vt[96 * 32];     // V tile transposed [d][key]
  __shared__ ushort_t Ps[4][16 * 32];  // per-wave P round-trip

  const int tid  = threadIdx.x;
  const int lane = tid & 63;
  const int l15  = lane & 15;
  const int quad = lane >> 4;
  const int wid  = tid >> 6;
  const int bh = blockIdx.y;
  const int b = bh >> 3;
  const int h = bh & 7;
  const int q0 = blockIdx.x * 64 + wid * 16;
  const size_t base = (size_t)b * 1024 * 2304;
  const int qoff = h * 96;

  // Q fragments: A-operand layout A[m=lane&15][k=quad*8+j], 3 chunks of K=32
  short8 qf[3];
#pragma unroll
  for (int c = 0; c < 3; ++c)
    qf[c] = *(const short8*)(qkv + base + (size_t)(q0 + l15) * 2304 + qoff +
                             c * 32 + quad * 8);

  float m_i[4] = {NEG_BIG, NEG_BIG, NEG_BIG, NEG_BIG};
  float l_i[4] = {0.f, 0.f, 0.f, 0.f};
  floatx4 O[6] = {};

  const int kend = blockIdx.x * 64 + 64;
  const float scale = 0.10206207261596577f;  // 1/sqrt(96)

  for (int k0 = 0; k0 < kend; k0 += 32) {
    // stage K tile (32x96), 8B vector loads
#pragma unroll
    for (int g = 0; g < 3; ++g) {
      int e = tid * 4 + g * 1024;
      int kr = e / 96, kc = e % 96;
      *(ushort4v*)&Ks[e] = *(const ushort4v*)(
          qkv + base + (size_t)(k0 + kr) * 2304 + 768 + qoff + kc);
    }
    // stage V transposed (scalar)
#pragma unroll
    for (int g = 0; g < 12; ++g) {
      int e = tid + g * 256;
      int kr = e / 96, kc = e % 96;
      Vt[kc * 32 + kr] = qkv[base + (size_t)(k0 + kr) * 2304 + 1536 + qoff + kc];
    }
    __syncthreads();

    if (k0 < q0 + 16) {  // wave-uniform: tile has at least one unmasked column
      floatx4 s0v = {0.f, 0.f, 0.f, 0.f}, s1v = {0.f, 0.f, 0.f, 0.f};
#pragma unroll
      for (int c = 0; c < 3; ++c) {
        short8 k0f = *(const short8*)&Ks[(l15) * 96 + c * 32 + quad * 8];
        short8 k1f = *(const short8*)&Ks[(16 + l15) * 96 + c * 32 + quad * 8];
        s0v = MFMA16(qf[c], k0f, s0v);
        s1v = MFMA16(qf[c], k1f, s1v);
      }
#pragma unroll
      for (int j = 0; j < 4; ++j) {
        const int rq = q0 + quad * 4 + j;
        float s0 = (k0 + l15      <= rq) ? s0v[j] * scale : NEG_BIG;
        float s1 = (k0 + 16 + l15 <= rq) ? s1v[j] * scale : NEG_BIG;
        float mt = fmaxf(s0, s1);
        mt = fmaxf(mt, __shfl_xor(mt, 1));
        mt = fmaxf(mt, __shfl_xor(mt, 2));
        mt = fmaxf(mt, __shfl_xor(mt, 4));
        mt = fmaxf(mt, __shfl_xor(mt, 8));
        const float mn = fmaxf(m_i[j], mt);     // finite always
        const float al = __expf(m_i[j] - mn);   // first tile: exp(-huge) = 0
        const float p0 = __expf(s0 - mn);
        const float p1 = __expf(s1 - mn);
        float rs = p0 + p1;
        rs += __shfl_xor(rs, 1);
        rs += __shfl_xor(rs, 2);
        rs += __shfl_xor(rs, 4);
        rs += __shfl_xor(rs, 8);
        l_i[j] = l_i[j] * al + rs;
        m_i[j] = mn;
#pragma unroll
        for (int f = 0; f < 6; ++f) O[f][j] *= al;
        Ps[wid][(quad * 4 + j) * 32 + l15]      = f2bf(p0);
        Ps[wid][(quad * 4 + j) * 32 + 16 + l15] = f2bf(p1);
      }
      asm volatile("s_waitcnt lgkmcnt(0)" ::: "memory");  // P write->read, in-wave
      union { short8 v; ushort_t s[8]; } pu;
#pragma unroll
      for (int t = 0; t < 8; ++t)
        pu.s[t] = Ps[wid][l15 * 32 + quad * 8 + t];
#pragma unroll
      for (int f = 0; f < 6; ++f) {
        short8 vf = *(const short8*)&Vt[(f * 16 + l15) * 32 + quad * 8];
        O[f] = MFMA16(pu.v, vf, O[f]);
      }
    }
    __syncthreads();
  }

#pragma unroll
  for (int j = 0; j < 4; ++j) {
    const float inv = 1.0f / fmaxf(l_i[j], 1e-20f);
    const size_t row = (size_t)b * 1024 + q0 + quad * 4 + j;
#pragma unroll
    for (int f = 0; f < 6; ++f)
      y[row * 768 + qoff + f * 16 + l15] = f2bf(O[f][j] * inv);
  }
}

// ---------------------------------------------------------------------------
extern "C" void kernel_launch(void* const* d_in, const int* in_sizes, int n_in,
                              void* d_out, int out_size, void* d_ws, size_t ws_size,
                              hipStream_t stream)
{
  const float* x_f  = (const float*)d_in[0];  // (8,1024,768) f32
  const float* wa_f = (const float*)d_in[1];  // (2304,768)   f32
  const float* ba_f = (const float*)d_in[2];  // (2304)       f32
  const float* wp_f = (const float*)d_in[3];  // (768,768)    f32
  const float* bp_f = (const float*)d_in[4];  // (768)        f32
  // d_in[5]: causal mask (int32) — unused
  float* out = (float*)d_out;                 // (8,1024,768) f32

  // workspace layout (bf16 ushort units)
  ushort_t* xb   = (ushort_t*)d_ws;                      // 8192 x  768
  ushort_t* wab  = xb  + (size_t)8192 * 768;             // 2304 x  768
  ushort_t* wpb  = wab + (size_t)2304 * 768;             //  768 x  768
  ushort_t* qkv  = wpb + (size_t)768 * 768;              // 8192 x 2304
  ushort_t* yw   = qkv + (size_t)8192 * 2304;            // 8192 x  768

  const int nx = 8192 * 768, nwa = 2304 * 768, nwp = 768 * 768;
  cvt_f32_bf16<<<(nx  / 4 + 255) / 256, 256, 0, stream>>>(x_f,  xb,  nx);
  cvt_f32_bf16<<<(nwa / 4 + 255) / 256, 256, 0, stream>>>(wa_f, wab, nwa);
  cvt_f32_bf16<<<(nwp / 4 + 255) / 256, 256, 0, stream>>>(wp_f, wpb, nwp);

  gemm_bt_bias<ushort_t><<<dim3(64, 18), 256, 0, stream>>>(
      xb, wab, ba_f, qkv, 8192, 2304, 768);
  attn_fused<<<dim3(16, 64), 256, 0, stream>>>(qkv, yw);
  gemm_bt_bias<float><<<dim3(64, 6), 256, 0, stream>>>(
      yw, wpb, bp_f, out, 8192, 768, 768);
}

// Round 4
// 251.323 us; speedup vs baseline: 1.4255x; 1.4255x over previous
//
#include <hip/hip_runtime.h>
#include <stdint.h>

// GPT causal self-attention block. B=8, T=1024, C=768, H=8, D=96. f32 I/O.
// bf16 MFMA pipeline with fp32 accumulation. Causal mask input ignored.

typedef unsigned short ushort_t;
typedef __attribute__((ext_vector_type(8))) short short8;     // 8 bf16 = 4 VGPRs
typedef __attribute__((ext_vector_type(4))) float floatx4;    // MFMA C/D frag
typedef __attribute__((ext_vector_type(4))) unsigned short ushort4v;

#define MFMA16(a, b, c) __builtin_amdgcn_mfma_f32_16x16x32_bf16(a, b, c, 0, 0, 0)
#define NEG_BIG (-1e30f)

__device__ __forceinline__ unsigned short f2bf(float f) {
  union { float f; unsigned int u; } v; v.f = f;
  unsigned int r = (v.u + 0x7FFFu + ((v.u >> 16) & 1u)) >> 16;  // RNE
  return (unsigned short)r;
}

__global__ __launch_bounds__(256) void cvt_f32_bf16(
    const float* __restrict__ in, ushort_t* __restrict__ out, int n)
{
  int i = (blockIdx.x * 256 + threadIdx.x) * 4;
  if (i + 3 < n) {
    float4 v = *(const float4*)(in + i);
    ushort4v o;
    o.x = f2bf(v.x); o.y = f2bf(v.y); o.z = f2bf(v.z); o.w = f2bf(v.w);
    *(ushort4v*)(out + i) = o;
  } else {
    for (; i < n; ++i) out[i] = f2bf(in[i]);
  }
}

// ---------------------------------------------------------------------------
// QKV GEMM: qkv = x @ Wqkv^T + b. Writes q,k into QK (row stride 1536) and
// v TRANSPOSED into VT[b][h][d][T] so attention never transposes in-kernel.
// m97 structure: 128x128 tile, BK=32, global_load_lds width=16, 4 waves 2x2.
// ---------------------------------------------------------------------------
__global__ __launch_bounds__(256) void gemm_qkv(
    const ushort_t* __restrict__ A,   // 8192 x 768 bf16 (x)
    const ushort_t* __restrict__ W,   // 2304 x 768 bf16
    const float* __restrict__ bias,   // 2304 f32
    ushort_t* __restrict__ QK,        // 8192 x 1536 bf16
    ushort_t* __restrict__ VT)        // (64 bh) x 96 x 1024 bf16
{
  const int K = 768, N = 2304;
  __shared__ ushort_t As[128 * 32];
  __shared__ ushort_t Bs[128 * 32];

  const int tid  = threadIdx.x;
  const int lane = tid & 63;
  const int l15  = lane & 15;
  const int quad = lane >> 4;
  const int wid  = tid >> 6;
  const int m0 = blockIdx.x * 128;
  const int n0 = blockIdx.y * 128;
  const int wm = (wid >> 1) * 64;
  const int wn = (wid & 1) * 64;
  const int srow = tid >> 2;
  const int scol = (tid & 3) * 8;

  floatx4 acc[4][4] = {};

  const ushort_t* gA = A + (size_t)(m0 + srow) * K + scol;
  const ushort_t* gB = W + (size_t)(n0 + srow) * K + scol;
  ushort_t* lA = &As[wid * 512];
  ushort_t* lB = &Bs[wid * 512];

  for (int k0 = 0; k0 < K; k0 += 32) {
    __builtin_amdgcn_global_load_lds(
        (const __attribute__((address_space(1))) void*)gA,
        (__attribute__((address_space(3))) void*)lA, 16, 0, 0);
    __builtin_amdgcn_global_load_lds(
        (const __attribute__((address_space(1))) void*)(gA + (size_t)64 * K),
        (__attribute__((address_space(3))) void*)(lA + 64 * 32), 16, 0, 0);
    __builtin_amdgcn_global_load_lds(
        (const __attribute__((address_space(1))) void*)gB,
        (__attribute__((address_space(3))) void*)lB, 16, 0, 0);
    __builtin_amdgcn_global_load_lds(
        (const __attribute__((address_space(1))) void*)(gB + (size_t)64 * K),
        (__attribute__((address_space(3))) void*)(lB + 64 * 32), 16, 0, 0);
    gA += 32; gB += 32;
    __syncthreads();

    short8 af[4], bf[4];
#pragma unroll
    for (int t = 0; t < 4; ++t)
      af[t] = *(const short8*)&As[(wm + t * 16 + l15) * 32 + quad * 8];
#pragma unroll
    for (int t = 0; t < 4; ++t)
      bf[t] = *(const short8*)&Bs[(wn + t * 16 + l15) * 32 + quad * 8];
#pragma unroll
    for (int tm = 0; tm < 4; ++tm)
#pragma unroll
      for (int tn = 0; tn < 4; ++tn)
        acc[tm][tn] = MFMA16(af[tm], bf[tn], acc[tm][tn]);
    __syncthreads();
  }

#pragma unroll
  for (int tn = 0; tn < 4; ++tn) {
    const int gc = n0 + wn + tn * 16 + l15;
    const float bv = bias[gc];
    const bool isv = (gc >= 1536);          // whole 16-col tile same side
    const int hh = (gc - 1536) / 96, dd = (gc - 1536) % 96;
#pragma unroll
    for (int tm = 0; tm < 4; ++tm) {
      const int gr = m0 + wm + tm * 16 + quad * 4;
#pragma unroll
      for (int r = 0; r < 4; ++r) {
        const float val = acc[tm][tn][r] + bv;
        const int row = gr + r;
        if (!isv) {
          QK[(size_t)row * 1536 + gc] = f2bf(val);
        } else {
          const int bb = row >> 10, tt = row & 1023;
          VT[(((size_t)(bb * 8 + hh)) * 96 + dd) * 1024 + tt] = f2bf(val);
        }
      }
    }
  }
}

// ---------------------------------------------------------------------------
// Generic GEMM (proj): C[m][n] = sum_k A[m][k] W[n][k] + bias[n], f32 out.
// ---------------------------------------------------------------------------
__global__ __launch_bounds__(256) void gemm_proj(
    const ushort_t* __restrict__ A,   // M x K bf16
    const ushort_t* __restrict__ W,   // N x K bf16
    const float* __restrict__ bias,   // N f32
    float* __restrict__ C,            // M x N f32
    int M, int N, int K)
{
  __shared__ ushort_t As[128 * 32];
  __shared__ ushort_t Bs[128 * 32];

  const int tid  = threadIdx.x;
  const int lane = tid & 63;
  const int l15  = lane & 15;
  const int quad = lane >> 4;
  const int wid  = tid >> 6;
  const int m0 = blockIdx.x * 128;
  const int n0 = blockIdx.y * 128;
  const int wm = (wid >> 1) * 64;
  const int wn = (wid & 1) * 64;
  const int srow = tid >> 2;
  const int scol = (tid & 3) * 8;

  floatx4 acc[4][4] = {};

  const ushort_t* gA = A + (size_t)(m0 + srow) * K + scol;
  const ushort_t* gB = W + (size_t)(n0 + srow) * K + scol;
  ushort_t* lA = &As[wid * 512];
  ushort_t* lB = &Bs[wid * 512];

  for (int k0 = 0; k0 < K; k0 += 32) {
    __builtin_amdgcn_global_load_lds(
        (const __attribute__((address_space(1))) void*)gA,
        (__attribute__((address_space(3))) void*)lA, 16, 0, 0);
    __builtin_amdgcn_global_load_lds(
        (const __attribute__((address_space(1))) void*)(gA + (size_t)64 * K),
        (__attribute__((address_space(3))) void*)(lA + 64 * 32), 16, 0, 0);
    __builtin_amdgcn_global_load_lds(
        (const __attribute__((address_space(1))) void*)gB,
        (__attribute__((address_space(3))) void*)lB, 16, 0, 0);
    __builtin_amdgcn_global_load_lds(
        (const __attribute__((address_space(1))) void*)(gB + (size_t)64 * K),
        (__attribute__((address_space(3))) void*)(lB + 64 * 32), 16, 0, 0);
    gA += 32; gB += 32;
    __syncthreads();

    short8 af[4], bf[4];
#pragma unroll
    for (int t = 0; t < 4; ++t)
      af[t] = *(const short8*)&As[(wm + t * 16 + l15) * 32 + quad * 8];
#pragma unroll
    for (int t = 0; t < 4; ++t)
      bf[t] = *(const short8*)&Bs[(wn + t * 16 + l15) * 32 + quad * 8];
#pragma unroll
    for (int tm = 0; tm < 4; ++tm)
#pragma unroll
      for (int tn = 0; tn < 4; ++tn)
        acc[tm][tn] = MFMA16(af[tm], bf[tn], acc[tm][tn]);
    __syncthreads();
  }

#pragma unroll
  for (int tn = 0; tn < 4; ++tn) {
    const int gc = n0 + wn + tn * 16 + l15;
    const float bv = bias[gc];
#pragma unroll
    for (int tm = 0; tm < 4; ++tm) {
      const int gr = m0 + wm + tm * 16 + quad * 4;
#pragma unroll
      for (int r = 0; r < 4; ++r)
        C[(size_t)(gr + r) * N + gc] = acc[tm][tn][r] + bv;
    }
  }
}

// ---------------------------------------------------------------------------
// Fused causal flash attention v2.
// Grid (16, 64): block = (b,h) + paired q-chunks cA=bx, cB=31-bx (32 rows ea).
// Waves 0,1 -> chunk A rows; waves 2,3 -> chunk B rows (16 q-rows per wave).
// BK=64 keys/tile. K staged via global_load_lds (packed [key][96]); V^T staged
// from pre-transposed VT with padded rows (72) for conflict-free b128 reads.
// ---------------------------------------------------------------------------
__global__ __launch_bounds__(256) void attn_fused(
    const ushort_t* __restrict__ QK,   // (B*T) x 1536 bf16  [q|k]
    const ushort_t* __restrict__ VT,   // (64 bh) x 96 x 1024 bf16
    ushort_t* __restrict__ y)          // (B*T) x 768 bf16
{
  __shared__ ushort_t Ks[64 * 96];     // packed: global_load_lds target
  __shared__ ushort_t Vt[96 * 72];     // padded rows (72) for b128 reads
  __shared__ ushort_t Ps[4][16 * 72];  // per-wave P round-trip, padded

  const int tid  = threadIdx.x;
  const int lane = tid & 63;
  const int l15  = lane & 15;
  const int quad = lane >> 4;
  const int wid  = tid >> 6;
  const int bh = blockIdx.y;
  const int b = bh >> 3;
  const int h = bh & 7;
  const int qoff = h * 96;

  const int cA = blockIdx.x;           // 0..15
  const int cB = 31 - cA;              // 16..31
  const int myChunk = (wid < 2) ? cA : cB;
  const int q0w = myChunk * 32 + (wid & 1) * 16;   // wave's first q row
  const int kend = cB * 32 + 32;                   // loop bound (chunk B)

  const size_t rowbase = (size_t)b * 1024;
  const ushort_t* vtb = VT + (size_t)bh * 96 * 1024;

  // Q fragments (A layout), K=96 in 3 chunks of 32
  short8 qf[3];
#pragma unroll
  for (int c = 0; c < 3; ++c)
    qf[c] = *(const short8*)(QK + (rowbase + q0w + l15) * 1536 + qoff +
                             c * 32 + quad * 8);

  float m_i[4] = {NEG_BIG, NEG_BIG, NEG_BIG, NEG_BIG};
  float l_i[4] = {0.f, 0.f, 0.f, 0.f};
  floatx4 O[6] = {};

  const float scale = 0.10206207261596577f;  // 1/sqrt(96)

  for (int k0 = 0; k0 < kend; k0 += 64) {
    // --- stage K tile [64][96] via global_load_lds (wave w -> keys w*16..+16)
#pragma unroll
    for (int i = 0; i < 3; ++i) {
      const int e = wid * 1536 + i * 512 + lane * 8;
      const int kr = e / 96, kc = e % 96;
      __builtin_amdgcn_global_load_lds(
          (const __attribute__((address_space(1))) void*)
              (QK + (rowbase + k0 + kr) * 1536 + 768 + qoff + kc),
          (__attribute__((address_space(3))) void*)(&Ks[wid * 1536 + i * 512]),
          16, 0, 0);
    }
    // --- stage V^T tile [96][64] -> padded LDS rows of 72
#pragma unroll
    for (int g = 0; g < 3; ++g) {
      const int d = g * 32 + (tid >> 3);
      const int kc = (tid & 7) * 8;
      short8 v = *(const short8*)(vtb + (size_t)d * 1024 + k0 + kc);
      *(short8*)&Vt[d * 72 + kc] = v;
    }
    __syncthreads();

    if (k0 < q0w + 16) {  // wave-uniform activity test
      // QK^T: 16 q-rows x 64 keys
      floatx4 s[4] = {};
#pragma unroll
      for (int t = 0; t < 4; ++t) {
#pragma unroll
        for (int c = 0; c < 3; ++c) {
          short8 kf = *(const short8*)&Ks[(t * 16 + l15) * 96 + c * 32 + quad * 8];
          s[t] = MFMA16(qf[c], kf, s[t]);
        }
      }
      // online softmax, 4 rows per lane (row = quad*4+j)
#pragma unroll
      for (int j = 0; j < 4; ++j) {
        const int rq = q0w + quad * 4 + j;
        float sv[4];
#pragma unroll
        for (int t = 0; t < 4; ++t)
          sv[t] = (k0 + t * 16 + l15 <= rq) ? s[t][j] * scale : NEG_BIG;
        float mt = fmaxf(fmaxf(sv[0], sv[1]), fmaxf(sv[2], sv[3]));
        mt = fmaxf(mt, __shfl_xor(mt, 1));
        mt = fmaxf(mt, __shfl_xor(mt, 2));
        mt = fmaxf(mt, __shfl_xor(mt, 4));
        mt = fmaxf(mt, __shfl_xor(mt, 8));
        const float mn = fmaxf(m_i[j], mt);
        const float al = __expf(m_i[j] - mn);
        float rs = 0.f;
#pragma unroll
        for (int t = 0; t < 4; ++t) {
          const float p = __expf(sv[t] - mn);
          rs += p;
          Ps[wid][(quad * 4 + j) * 72 + t * 16 + l15] = f2bf(p);
        }
        rs += __shfl_xor(rs, 1);
        rs += __shfl_xor(rs, 2);
        rs += __shfl_xor(rs, 4);
        rs += __shfl_xor(rs, 8);
        l_i[j] = l_i[j] * al + rs;
        m_i[j] = mn;
#pragma unroll
        for (int f = 0; f < 6; ++f) O[f][j] *= al;
      }
      asm volatile("s_waitcnt lgkmcnt(0)" ::: "memory");  // in-wave P w->r
      short8 pf[2];
#pragma unroll
      for (int u = 0; u < 2; ++u)
        pf[u] = *(const short8*)&Ps[wid][l15 * 72 + u * 32 + quad * 8];
#pragma unroll
      for (int u = 0; u < 2; ++u)
#pragma unroll
        for (int f = 0; f < 6; ++f) {
          short8 vf = *(const short8*)&Vt[(f * 16 + l15) * 72 + u * 32 + quad * 8];
          O[f] = MFMA16(pf[u], vf, O[f]);
        }
    }
    __syncthreads();
  }

#pragma unroll
  for (int j = 0; j < 4; ++j) {
    const float inv = 1.0f / fmaxf(l_i[j], 1e-20f);
    const size_t row = rowbase + q0w + quad * 4 + j;
#pragma unroll
    for (int f = 0; f < 6; ++f)
      y[row * 768 + qoff + f * 16 + l15] = f2bf(O[f][j] * inv);
  }
}

// ---------------------------------------------------------------------------
extern "C" void kernel_launch(void* const* d_in, const int* in_sizes, int n_in,
                              void* d_out, int out_size, void* d_ws, size_t ws_size,
                              hipStream_t stream)
{
  const float* x_f  = (const float*)d_in[0];
  const float* wa_f = (const float*)d_in[1];
  const float* ba_f = (const float*)d_in[2];
  const float* wp_f = (const float*)d_in[3];
  const float* bp_f = (const float*)d_in[4];
  float* out = (float*)d_out;

  ushort_t* xb  = (ushort_t*)d_ws;                    // 8192 x  768
  ushort_t* wab = xb  + (size_t)8192 * 768;           // 2304 x  768
  ushort_t* wpb = wab + (size_t)2304 * 768;           //  768 x  768
  ushort_t* QK  = wpb + (size_t)768 * 768;            // 8192 x 1536
  ushort_t* VT  = QK  + (size_t)8192 * 1536;          // 64 x 96 x 1024
  ushort_t* yw  = VT  + (size_t)8192 * 768;           // 8192 x  768

  const int nx = 8192 * 768, nwa = 2304 * 768, nwp = 768 * 768;
  cvt_f32_bf16<<<(nx  / 4 + 255) / 256, 256, 0, stream>>>(x_f,  xb,  nx);
  cvt_f32_bf16<<<(nwa / 4 + 255) / 256, 256, 0, stream>>>(wa_f, wab, nwa);
  cvt_f32_bf16<<<(nwp / 4 + 255) / 256, 256, 0, stream>>>(wp_f, wpb, nwp);

  gemm_qkv<<<dim3(64, 18), 256, 0, stream>>>(xb, wab, ba_f, QK, VT);
  attn_fused<<<dim3(16, 64), 256, 0, stream>>>(QK, VT, yw);
  gemm_proj<<<dim3(64, 6), 256, 0, stream>>>(yw, wpb, bp_f, out,
                                             8192, 768, 768);
}